// Round 16
// baseline (153.435 us; speedup 1.0000x reference)
//
#include <hip/hip_runtime.h>

#define HW_N 1048576
#define C_IN 64
#define K_CLS 4096
#define H1_N 256
#define NCLS_N 16
#define SCAT_BLOCKS 256
#define ROWS_PER_SCAT (HW_N / SCAT_BLOCKS)  // 4096
#define CAP 512                              // slots per cluster (max n ~ 336)
#define CLPB 4                               // clusters per mega block (1/wave)

__device__ __forceinline__ float silu_f(float x) {
  return x / (1.0f + expf(-x));
}

// Degree-3 B-spline bases on the uniform grid g[j] = 0.4*(j-3) - 1, j=0..11.
__device__ __forceinline__ void bspline8(float x, float* b) {
  float t[11];
#pragma unroll
  for (int j = 0; j < 11; ++j) {
    float g0 = 0.4f * (float)(j - 3) - 1.0f;
    float g1 = 0.4f * (float)(j - 2) - 1.0f;
    t[j] = (x >= g0 && x < g1) ? 1.0f : 0.0f;
  }
#pragma unroll
  for (int k = 1; k <= 3; ++k) {
#pragma unroll 10
    for (int j = 0; j + k < 11; ++j) {
      float gj   = 0.4f * (float)(j - 3) - 1.0f;
      float gj1  = 0.4f * (float)(j - 2) - 1.0f;
      float gjk  = 0.4f * (float)(j + k - 3) - 1.0f;
      float gjk1 = 0.4f * (float)(j + k - 2) - 1.0f;
      float left  = (x - gj) / (gjk - gj);
      float right = (gjk1 - x) / (gjk1 - gj1);
      t[j] = left * t[j] + right * t[j + 1];
    }
  }
#pragma unroll
  for (int g = 0; g < 8; ++g) b[g] = t[g];
}

// ---- Fused weight transposes + ccnt zeroing ----
__global__ __launch_bounds__(256) void transpose_w(
    const float* __restrict__ bw1, const float* __restrict__ sw1,
    const float* __restrict__ sc1, const float* __restrict__ bw2,
    const float* __restrict__ sw2, const float* __restrict__ sc2,
    float* __restrict__ bwt1, float* __restrict__ swt1,
    float* __restrict__ bwt2, float* __restrict__ swt2,
    int* __restrict__ ccnt) {
  int bid = blockIdx.x, tid = threadIdx.x;
  if (bid < C_IN) {
    int i = bid, o = tid;
    float sc = sc1[o * C_IN + i];
    bwt1[i * H1_N + o] = bw1[o * C_IN + i];
    const float4* src = (const float4*)&sw1[(size_t)(o * C_IN + i) * 8];
    float4 a = src[0], b = src[1];
    a.x *= sc; a.y *= sc; a.z *= sc; a.w *= sc;
    b.x *= sc; b.y *= sc; b.z *= sc; b.w *= sc;
    float4* dst = (float4*)&swt1[(size_t)(i * H1_N + o) * 8];
    dst[0] = a; dst[1] = b;
  } else if (bid < C_IN + H1_N / 2) {
    int gi = (bid - C_IN) * 2 + (tid >> 7);
    int t = tid & 127;
    int o = t >> 3, e = t & 7;
    swt2[(gi * NCLS_N + o) * 8 + e] =
        sw2[(size_t)(o * H1_N + gi) * 8 + e] * sc2[o * H1_N + gi];
    if (t < NCLS_N) bwt2[gi * NCLS_N + t] = bw2[t * H1_N + gi];
  } else {
    ccnt[(bid - C_IN - H1_N / 2) * 256 + tid] = 0;
  }
}

// ---- Scatter: block-aggregated atomic slot reservation ----
__global__ __launch_bounds__(1024) void scatter_atomic(
    const int* __restrict__ cls, int* __restrict__ ccnt,
    int* __restrict__ spk) {
  __shared__ int lhist[K_CLS];  // 16 KB
  int b = blockIdx.x, tid = threadIdx.x;
  for (int c = tid; c < K_CLS; c += 1024) lhist[c] = 0;
  __syncthreads();
  int r0 = b * ROWS_PER_SCAT;
  for (int r = r0 + tid; r < r0 + ROWS_PER_SCAT; r += 1024)
    atomicAdd(&lhist[cls[r]], 1);
  __syncthreads();
  for (int c = tid; c < K_CLS; c += 1024) {
    int n = lhist[c];
    lhist[c] = n ? atomicAdd(&ccnt[c], n) : 0;
  }
  __syncthreads();
  for (int r = r0 + tid; r < r0 + ROWS_PER_SCAT; r += 1024) {
    int c = cls[r];
    int pos = atomicAdd(&lhist[c], 1);
    spk[(size_t)c * CAP + pos] = r;
  }
}

// ---- Mega v6: 1024 blocks x 256 thr, 4 clusters/block, wave = cluster ----
// r13's proven per-wave gather, finer block grain (4 dispatch rounds) for
// tail balance. (256,6): 6 blocks/CU = 24 waves/CU @ ~85 VGPR (no spill).
__global__ __launch_bounds__(256, 6) void mega(
    const float* __restrict__ x, const int* __restrict__ spk,
    const int* __restrict__ ccnt, const float* __restrict__ bwt1,
    const float* __restrict__ swt1, const float* __restrict__ bwt2,
    const float* __restrict__ swt2, float* __restrict__ out) {
  __shared__ float s_bases[4][516];    // 8.25 KB (aliased as sac in epilogue)
  __shared__ float s_silu[4][65];      // 1 KB
  __shared__ float mean_sacc[4][65];   // 1 KB
  __shared__ float h_lds[4][257];      // 4.1 KB

  int bid = blockIdx.x, tid = threadIdx.x;
  int wv = tid >> 6, lane = tid & 63;
  int g = lane >> 4, q = lane & 15;

  // ---- phase 1: wave wv gathers cluster bid*4+wv (8-deep, idx-prefetch) ----
  {
    int cidx = bid * CLPB + wv;
    int n = ccnt[cidx];  // wave-uniform -> scalar load
    const int* sid = spk + (size_t)cidx * CAP;
    const float4* x4 = (const float4*)x;
    float ax = 0.0f, ay = 0.0f, az = 0.0f, aw = 0.0f;
    int i = g;
    if (i + 28 < n) {
      int pa0 = sid[i],      pa1 = sid[i + 4],  pa2 = sid[i + 8],  pa3 = sid[i + 12];
      int pa4 = sid[i + 16], pa5 = sid[i + 20], pa6 = sid[i + 24], pa7 = sid[i + 28];
      while (true) {
        float4 v0 = x4[(size_t)pa0 * 16 + q];
        float4 v1 = x4[(size_t)pa1 * 16 + q];
        float4 v2 = x4[(size_t)pa2 * 16 + q];
        float4 v3 = x4[(size_t)pa3 * 16 + q];
        float4 v4 = x4[(size_t)pa4 * 16 + q];
        float4 v5 = x4[(size_t)pa5 * 16 + q];
        float4 v6 = x4[(size_t)pa6 * 16 + q];
        float4 v7 = x4[(size_t)pa7 * 16 + q];
        int ib = i + 32;  // prefetch next batch's indices (in-bounds: < CAP)
        int pb0 = sid[ib],      pb1 = sid[ib + 4],  pb2 = sid[ib + 8],  pb3 = sid[ib + 12];
        int pb4 = sid[ib + 16], pb5 = sid[ib + 20], pb6 = sid[ib + 24], pb7 = sid[ib + 28];
        float tx0 = v0.x + v1.x, tx1 = v2.x + v3.x, tx2 = v4.x + v5.x, tx3 = v6.x + v7.x;
        float ty0 = v0.y + v1.y, ty1 = v2.y + v3.y, ty2 = v4.y + v5.y, ty3 = v6.y + v7.y;
        float tz0 = v0.z + v1.z, tz1 = v2.z + v3.z, tz2 = v4.z + v5.z, tz3 = v6.z + v7.z;
        float tw0 = v0.w + v1.w, tw1 = v2.w + v3.w, tw2 = v4.w + v5.w, tw3 = v6.w + v7.w;
        ax += (tx0 + tx1) + (tx2 + tx3);
        ay += (ty0 + ty1) + (ty2 + ty3);
        az += (tz0 + tz1) + (tz2 + tz3);
        aw += (tw0 + tw1) + (tw2 + tw3);
        i = ib;
        pa0 = pb0; pa1 = pb1; pa2 = pb2; pa3 = pb3;
        pa4 = pb4; pa5 = pb5; pa6 = pb6; pa7 = pb7;
        if (!(i + 28 < n)) break;
      }
    }
    if (i < n) {  // predicated 8-deep tail
      int nm1 = n - 1;
      int i1 = i + 4, i2 = i + 8, i3 = i + 12, i4 = i + 16, i5 = i + 20,
          i6 = i + 24, i7 = i + 28;
      int p0 = sid[i];
      int p1 = sid[i1 < nm1 ? i1 : nm1];
      int p2 = sid[i2 < nm1 ? i2 : nm1];
      int p3 = sid[i3 < nm1 ? i3 : nm1];
      int p4 = sid[i4 < nm1 ? i4 : nm1];
      int p5 = sid[i5 < nm1 ? i5 : nm1];
      int p6 = sid[i6 < nm1 ? i6 : nm1];
      int p7 = sid[i7 < nm1 ? i7 : nm1];
      float4 v0 = x4[(size_t)p0 * 16 + q];
      float4 v1 = x4[(size_t)p1 * 16 + q];
      float4 v2 = x4[(size_t)p2 * 16 + q];
      float4 v3 = x4[(size_t)p3 * 16 + q];
      float4 v4 = x4[(size_t)p4 * 16 + q];
      float4 v5 = x4[(size_t)p5 * 16 + q];
      float4 v6 = x4[(size_t)p6 * 16 + q];
      float4 v7 = x4[(size_t)p7 * 16 + q];
      ax += v0.x; ay += v0.y; az += v0.z; aw += v0.w;
      if (i1 < n) { ax += v1.x; ay += v1.y; az += v1.z; aw += v1.w; }
      if (i2 < n) { ax += v2.x; ay += v2.y; az += v2.z; aw += v2.w; }
      if (i3 < n) { ax += v3.x; ay += v3.y; az += v3.z; aw += v3.w; }
      if (i4 < n) { ax += v4.x; ay += v4.y; az += v4.z; aw += v4.w; }
      if (i5 < n) { ax += v5.x; ay += v5.y; az += v5.z; aw += v5.w; }
      if (i6 < n) { ax += v6.x; ay += v6.y; az += v6.z; aw += v6.w; }
      if (i7 < n) { ax += v7.x; ay += v7.y; az += v7.z; aw += v7.w; }
    }
    // reduce the 4 g-partials within the wave
    ax += __shfl_xor(ax, 16); ax += __shfl_xor(ax, 32);
    ay += __shfl_xor(ay, 16); ay += __shfl_xor(ay, 32);
    az += __shfl_xor(az, 16); az += __shfl_xor(az, 32);
    aw += __shfl_xor(aw, 16); aw += __shfl_xor(aw, 32);
    if (g == 0) {
      float inv = 1.0f / fmaxf((float)n, 1.0f);
      mean_sacc[wv][q * 4 + 0] = ax * inv;
      mean_sacc[wv][q * 4 + 1] = ay * inv;
      mean_sacc[wv][q * 4 + 2] = az * inv;
      mean_sacc[wv][q * 4 + 3] = aw * inv;
    }
  }
  __syncthreads();

  // ---- phase 2: stage silu + bases of 4 mean rows (1 item/thread) ----
  {
    int r = tid >> 6, i = tid & 63;
    float xv = mean_sacc[r][i];
    s_silu[r][i] = silu_f(xv);
    float b[8];
    bspline8(xv, b);
    float4* dst = (float4*)&s_bases[r][i * 8];
    dst[0] = make_float4(b[0], b[1], b[2], b[3]);
    dst[1] = make_float4(b[4], b[5], b[6], b[7]);
  }
  __syncthreads();

  // ---- phase 3: kan1; o = tid, acc[4], full i range ----
  {
    int o = tid;
    float acc[4];
#pragma unroll
    for (int r = 0; r < 4; ++r) acc[r] = 0.0f;
    for (int i = 0; i < C_IN; ++i) {
      float wb = bwt1[i * H1_N + o];
      const float4* wp = (const float4*)&swt1[(size_t)(i * H1_N + o) * 8];
      float4 w0 = wp[0], w1 = wp[1];
#pragma unroll
      for (int r = 0; r < 4; ++r) {
        float sv = s_silu[r][i];
        const float4* bp = (const float4*)&s_bases[r][i * 8];
        float4 b0 = bp[0], b1 = bp[1];
        float a = acc[r];
        a = fmaf(sv, wb, a);
        a = fmaf(b0.x, w0.x, a); a = fmaf(b0.y, w0.y, a);
        a = fmaf(b0.z, w0.z, a); a = fmaf(b0.w, w0.w, a);
        a = fmaf(b1.x, w1.x, a); a = fmaf(b1.y, w1.y, a);
        a = fmaf(b1.z, w1.z, a); a = fmaf(b1.w, w1.w, a);
        acc[r] = a;
      }
    }
    __syncthreads();  // phase-2 reads complete before h_lds write / re-stage
#pragma unroll
    for (int r = 0; r < 4; ++r) h_lds[r][o] = acc[r];
  }
  __syncthreads();

  // ---- phase 4: kan2; (o2, rr, jh) = (tid&15, (tid>>4)&3, tid>>6) ----
  {
    int o2 = tid & 15, rr = (tid >> 4) & 3, jh = tid >> 6;  // jh in 0..3
    float acc2 = 0.0f;
    for (int ic0 = 0; ic0 < H1_N; ic0 += 64) {
      {  // stage chunk (1 item/thread)
        int r = tid >> 6, i = tid & 63;
        float xv = h_lds[r][ic0 + i];
        s_silu[r][i] = silu_f(xv);
        float b[8];
        bspline8(xv, b);
        float4* dst = (float4*)&s_bases[r][i * 8];
        dst[0] = make_float4(b[0], b[1], b[2], b[3]);
        dst[1] = make_float4(b[4], b[5], b[6], b[7]);
      }
      __syncthreads();
      int ib = jh * 16;
      for (int i = ib; i < ib + 16; ++i) {
        int gi = ic0 + i;
        float wb = bwt2[gi * NCLS_N + o2];
        const float4* wp = (const float4*)&swt2[(gi * NCLS_N + o2) * 8];
        float4 w0 = wp[0], w1 = wp[1];
        float sv = s_silu[rr][i];
        const float4* bp = (const float4*)&s_bases[rr][i * 8];
        float4 b0 = bp[0], b1 = bp[1];
        float sp = b0.x * w0.x + b0.y * w0.y + b0.z * w0.z + b0.w * w0.w
                 + b1.x * w1.x + b1.y * w1.y + b1.z * w1.z + b1.w * w1.w;
        acc2 = fmaf(sv, wb, acc2);
        acc2 += sp;
      }
      __syncthreads();
    }
    // reduce 4 jh-partials via the (dead) s_bases buffer
    float* sac = &s_bases[0][0];
    sac[jh * 64 + rr * 16 + o2] = acc2;
    __syncthreads();
    if (tid < 64) {
      float s = sac[tid] + sac[64 + tid] + sac[128 + tid] + sac[192 + tid];
      out[(bid * CLPB + (tid >> 4)) * NCLS_N + (tid & 15)] = s;
    }
  }
}

extern "C" void kernel_launch(void* const* d_in, const int* in_sizes, int n_in,
                              void* d_out, int out_size, void* d_ws, size_t ws_size,
                              hipStream_t stream) {
  const float* x   = (const float*)d_in[0];
  const int*   cls = (const int*)d_in[1];
  const float* bw1 = (const float*)d_in[2];
  const float* sw1 = (const float*)d_in[3];
  const float* sc1 = (const float*)d_in[4];
  const float* bw2 = (const float*)d_in[5];
  const float* sw2 = (const float*)d_in[6];
  const float* sc2 = (const float*)d_in[7];
  float* out = (float*)d_out;

  int*   ccnt = (int*)d_ws;                     // 4096         (16 KB)
  int*   spk  = ccnt + K_CLS;                   // 4096*512     (8 MB)
  float* swt1 = (float*)(spk + K_CLS * CAP);    // 64*256*8     (512 KB)
  float* bwt1 = swt1 + C_IN * H1_N * 8;         // 64*256
  float* swt2 = bwt1 + C_IN * H1_N;             // 256*16*8     (128 KB)
  float* bwt2 = swt2 + H1_N * NCLS_N * 8;       // 256*16

  transpose_w<<<C_IN + H1_N / 2 + K_CLS / 256, 256, 0, stream>>>(
      bw1, sw1, sc1, bw2, sw2, sc2, bwt1, swt1, bwt2, swt2, ccnt);
  scatter_atomic<<<SCAT_BLOCKS, 1024, 0, stream>>>(cls, ccnt, spk);
  mega<<<K_CLS / CLPB, 256, 0, stream>>>(
      x, spk, ccnt, bwt1, swt1, bwt2, swt2, out);
}

// Round 17
// 127.840 us; speedup vs baseline: 1.2002x; 1.2002x over previous
//
#include <hip/hip_runtime.h>

#define HW_N 1048576
#define C_IN 64
#define K_CLS 4096
#define H1_N 256
#define NCLS_N 16
#define SCAT_BLOCKS 256
#define ROWS_PER_SCAT (HW_N / SCAT_BLOCKS)  // 4096
#define CAP 512                              // slots per cluster (max n ~ 336)
#define CLPB 8                               // clusters per mega block (1/wave)

__device__ __forceinline__ float silu_f(float x) {
  return x / (1.0f + expf(-x));
}

// Degree-3 B-spline bases on the uniform grid g[j] = 0.4*(j-3) - 1, j=0..11.
__device__ __forceinline__ void bspline8(float x, float* b) {
  float t[11];
#pragma unroll
  for (int j = 0; j < 11; ++j) {
    float g0 = 0.4f * (float)(j - 3) - 1.0f;
    float g1 = 0.4f * (float)(j - 2) - 1.0f;
    t[j] = (x >= g0 && x < g1) ? 1.0f : 0.0f;
  }
#pragma unroll
  for (int k = 1; k <= 3; ++k) {
#pragma unroll 10
    for (int j = 0; j + k < 11; ++j) {
      float gj   = 0.4f * (float)(j - 3) - 1.0f;
      float gj1  = 0.4f * (float)(j - 2) - 1.0f;
      float gjk  = 0.4f * (float)(j + k - 3) - 1.0f;
      float gjk1 = 0.4f * (float)(j + k - 2) - 1.0f;
      float left  = (x - gj) / (gjk - gj);
      float right = (gjk1 - x) / (gjk1 - gj1);
      t[j] = left * t[j] + right * t[j + 1];
    }
  }
#pragma unroll
  for (int g = 0; g < 8; ++g) b[g] = t[g];
}

// ---- Fused weight transposes + ccnt zeroing ----
__global__ __launch_bounds__(256) void transpose_w(
    const float* __restrict__ bw1, const float* __restrict__ sw1,
    const float* __restrict__ sc1, const float* __restrict__ bw2,
    const float* __restrict__ sw2, const float* __restrict__ sc2,
    float* __restrict__ bwt1, float* __restrict__ swt1,
    float* __restrict__ bwt2, float* __restrict__ swt2,
    int* __restrict__ ccnt) {
  int bid = blockIdx.x, tid = threadIdx.x;
  if (bid < C_IN) {
    int i = bid, o = tid;
    float sc = sc1[o * C_IN + i];
    bwt1[i * H1_N + o] = bw1[o * C_IN + i];
    const float4* src = (const float4*)&sw1[(size_t)(o * C_IN + i) * 8];
    float4 a = src[0], b = src[1];
    a.x *= sc; a.y *= sc; a.z *= sc; a.w *= sc;
    b.x *= sc; b.y *= sc; b.z *= sc; b.w *= sc;
    float4* dst = (float4*)&swt1[(size_t)(i * H1_N + o) * 8];
    dst[0] = a; dst[1] = b;
  } else if (bid < C_IN + H1_N / 2) {
    int gi = (bid - C_IN) * 2 + (tid >> 7);
    int t = tid & 127;
    int o = t >> 3, e = t & 7;
    swt2[(gi * NCLS_N + o) * 8 + e] =
        sw2[(size_t)(o * H1_N + gi) * 8 + e] * sc2[o * H1_N + gi];
    if (t < NCLS_N) bwt2[gi * NCLS_N + t] = bw2[t * H1_N + gi];
  } else {
    ccnt[(bid - C_IN - H1_N / 2) * 256 + tid] = 0;
  }
}

// ---- Scatter: block-aggregated atomic slot reservation ----
__global__ __launch_bounds__(1024) void scatter_atomic(
    const int* __restrict__ cls, int* __restrict__ ccnt,
    int* __restrict__ spk) {
  __shared__ int lhist[K_CLS];  // 16 KB
  int b = blockIdx.x, tid = threadIdx.x;
  for (int c = tid; c < K_CLS; c += 1024) lhist[c] = 0;
  __syncthreads();
  int r0 = b * ROWS_PER_SCAT;
  for (int r = r0 + tid; r < r0 + ROWS_PER_SCAT; r += 1024)
    atomicAdd(&lhist[cls[r]], 1);
  __syncthreads();
  for (int c = tid; c < K_CLS; c += 1024) {
    int n = lhist[c];
    lhist[c] = n ? atomicAdd(&ccnt[c], n) : 0;
  }
  __syncthreads();
  for (int r = r0 + tid; r < r0 + ROWS_PER_SCAT; r += 1024) {
    int c = cls[r];
    int pos = atomicAdd(&lhist[c], 1);
    spk[(size_t)c * CAP + pos] = r;
  }
}

// ---- Mega v3 (best measured): idx-prefetch pipelined gather -> kan1 -> kan2 ----
// 512 blocks x 512 thr (wave = cluster), launch_bounds(512,4): 2 blocks/CU,
// 16 waves/CU, ~128-VGPR budget -> 8-deep pipeline with zero spills.
__global__ __launch_bounds__(512, 4) void mega(
    const float* __restrict__ x, const int* __restrict__ spk,
    const int* __restrict__ ccnt, const float* __restrict__ bwt1,
    const float* __restrict__ swt1, const float* __restrict__ bwt2,
    const float* __restrict__ swt2, float* __restrict__ out) {
  __shared__ float s_bases[8][516];   // 16.5 KB
  __shared__ float s_silu[8][65];     // 2 KB
  __shared__ float mean_sacc[8][65];  // 2 KB: mean (ph1-2); sacc2 (ph4)
  __shared__ float h_lds[8][257];     // 8.2 KB

  int bid = blockIdx.x, tid = threadIdx.x;
  int wv = tid >> 6, lane = tid & 63;
  int g = lane >> 4, q = lane & 15;

  // ---- phase 1: wave wv gathers cluster bid*8+wv (idx-prefetch pipeline) ----
  {
    int cidx = bid * CLPB + wv;
    int n = ccnt[cidx];  // wave-uniform -> scalar load, no barrier needed
    const int* sid = spk + (size_t)cidx * CAP;
    const float4* x4 = (const float4*)x;
    float ax = 0.0f, ay = 0.0f, az = 0.0f, aw = 0.0f;
    int i = g;
    if (i + 28 < n) {
      int pa0 = sid[i],      pa1 = sid[i + 4],  pa2 = sid[i + 8],  pa3 = sid[i + 12];
      int pa4 = sid[i + 16], pa5 = sid[i + 20], pa6 = sid[i + 24], pa7 = sid[i + 28];
      while (true) {
        // issue current batch's x-loads
        float4 v0 = x4[(size_t)pa0 * 16 + q];
        float4 v1 = x4[(size_t)pa1 * 16 + q];
        float4 v2 = x4[(size_t)pa2 * 16 + q];
        float4 v3 = x4[(size_t)pa3 * 16 + q];
        float4 v4 = x4[(size_t)pa4 * 16 + q];
        float4 v5 = x4[(size_t)pa5 * 16 + q];
        float4 v6 = x4[(size_t)pa6 * 16 + q];
        float4 v7 = x4[(size_t)pa7 * 16 + q];
        // prefetch next batch's indices (always in-bounds: < CAP)
        int ib = i + 32;
        int pb0 = sid[ib],      pb1 = sid[ib + 4],  pb2 = sid[ib + 8],  pb3 = sid[ib + 12];
        int pb4 = sid[ib + 16], pb5 = sid[ib + 20], pb6 = sid[ib + 24], pb7 = sid[ib + 28];
        // consume current batch
        float tx0 = v0.x + v1.x, tx1 = v2.x + v3.x, tx2 = v4.x + v5.x, tx3 = v6.x + v7.x;
        float ty0 = v0.y + v1.y, ty1 = v2.y + v3.y, ty2 = v4.y + v5.y, ty3 = v6.y + v7.y;
        float tz0 = v0.z + v1.z, tz1 = v2.z + v3.z, tz2 = v4.z + v5.z, tz3 = v6.z + v7.z;
        float tw0 = v0.w + v1.w, tw1 = v2.w + v3.w, tw2 = v4.w + v5.w, tw3 = v6.w + v7.w;
        ax += (tx0 + tx1) + (tx2 + tx3);
        ay += (ty0 + ty1) + (ty2 + ty3);
        az += (tz0 + tz1) + (tz2 + tz3);
        aw += (tw0 + tw1) + (tw2 + tw3);
        i = ib;
        pa0 = pb0; pa1 = pb1; pa2 = pb2; pa3 = pb3;
        pa4 = pb4; pa5 = pb5; pa6 = pb6; pa7 = pb7;
        if (!(i + 28 < n)) break;
      }
    }
    if (i < n) {  // predicated 8-deep tail (remaining <= 8 rows per thread)
      int nm1 = n - 1;
      int i1 = i + 4, i2 = i + 8, i3 = i + 12, i4 = i + 16, i5 = i + 20,
          i6 = i + 24, i7 = i + 28;
      int p0 = sid[i];
      int p1 = sid[i1 < nm1 ? i1 : nm1];
      int p2 = sid[i2 < nm1 ? i2 : nm1];
      int p3 = sid[i3 < nm1 ? i3 : nm1];
      int p4 = sid[i4 < nm1 ? i4 : nm1];
      int p5 = sid[i5 < nm1 ? i5 : nm1];
      int p6 = sid[i6 < nm1 ? i6 : nm1];
      int p7 = sid[i7 < nm1 ? i7 : nm1];
      float4 v0 = x4[(size_t)p0 * 16 + q];
      float4 v1 = x4[(size_t)p1 * 16 + q];
      float4 v2 = x4[(size_t)p2 * 16 + q];
      float4 v3 = x4[(size_t)p3 * 16 + q];
      float4 v4 = x4[(size_t)p4 * 16 + q];
      float4 v5 = x4[(size_t)p5 * 16 + q];
      float4 v6 = x4[(size_t)p6 * 16 + q];
      float4 v7 = x4[(size_t)p7 * 16 + q];
      ax += v0.x; ay += v0.y; az += v0.z; aw += v0.w;
      if (i1 < n) { ax += v1.x; ay += v1.y; az += v1.z; aw += v1.w; }
      if (i2 < n) { ax += v2.x; ay += v2.y; az += v2.z; aw += v2.w; }
      if (i3 < n) { ax += v3.x; ay += v3.y; az += v3.z; aw += v3.w; }
      if (i4 < n) { ax += v4.x; ay += v4.y; az += v4.z; aw += v4.w; }
      if (i5 < n) { ax += v5.x; ay += v5.y; az += v5.z; aw += v5.w; }
      if (i6 < n) { ax += v6.x; ay += v6.y; az += v6.z; aw += v6.w; }
      if (i7 < n) { ax += v7.x; ay += v7.y; az += v7.z; aw += v7.w; }
    }
    // reduce the 4 g-partials within the wave
    ax += __shfl_xor(ax, 16); ax += __shfl_xor(ax, 32);
    ay += __shfl_xor(ay, 16); ay += __shfl_xor(ay, 32);
    az += __shfl_xor(az, 16); az += __shfl_xor(az, 32);
    aw += __shfl_xor(aw, 16); aw += __shfl_xor(aw, 32);
    if (g == 0) {
      float inv = 1.0f / fmaxf((float)n, 1.0f);
      mean_sacc[wv][q * 4 + 0] = ax * inv;
      mean_sacc[wv][q * 4 + 1] = ay * inv;
      mean_sacc[wv][q * 4 + 2] = az * inv;
      mean_sacc[wv][q * 4 + 3] = aw * inv;
    }
  }
  __syncthreads();

  // ---- phase 2: stage silu + bases of 8 mean rows (1 item/thread) ----
  {
    int r = tid >> 6, i = tid & 63;
    float xv = mean_sacc[r][i];
    s_silu[r][i] = silu_f(xv);
    float b[8];
    bspline8(xv, b);
    float4* dst = (float4*)&s_bases[r][i * 8];
    dst[0] = make_float4(b[0], b[1], b[2], b[3]);
    dst[1] = make_float4(b[4], b[5], b[6], b[7]);
  }
  __syncthreads();

  // ---- phase 3: kan1; (o, ih) = (tid&255, tid>>8) ----
  {
    int o = tid & 255, ih = tid >> 8;
    float acc[8];
#pragma unroll
    for (int r = 0; r < 8; ++r) acc[r] = 0.0f;
    int i0 = ih * 32;
    for (int i = i0; i < i0 + 32; ++i) {
      float wb = bwt1[i * H1_N + o];
      const float4* wp = (const float4*)&swt1[(size_t)(i * H1_N + o) * 8];
      float4 w0 = wp[0], w1 = wp[1];
#pragma unroll
      for (int r = 0; r < 8; ++r) {
        float sv = s_silu[r][i];
        const float4* bp = (const float4*)&s_bases[r][i * 8];
        float4 b0 = bp[0], b1 = bp[1];
        float a = acc[r];
        a = fmaf(sv, wb, a);
        a = fmaf(b0.x, w0.x, a); a = fmaf(b0.y, w0.y, a);
        a = fmaf(b0.z, w0.z, a); a = fmaf(b0.w, w0.w, a);
        a = fmaf(b1.x, w1.x, a); a = fmaf(b1.y, w1.y, a);
        a = fmaf(b1.z, w1.z, a); a = fmaf(b1.w, w1.w, a);
        acc[r] = a;
      }
    }
    if (ih == 0) {
#pragma unroll
      for (int r = 0; r < 8; ++r) h_lds[r][o] = acc[r];
    }
    __syncthreads();
    if (ih == 1) {
#pragma unroll
      for (int r = 0; r < 8; ++r) h_lds[r][o] += acc[r];
    }
  }
  __syncthreads();

  // ---- phase 4: kan2; (o2, rr, jh) = (tid&15, (tid>>4)&7, tid>>7) ----
  {
    int o2 = tid & 15, rr = (tid >> 4) & 7, jh = tid >> 7;  // jh in 0..3
    float acc2 = 0.0f;
    for (int ic0 = 0; ic0 < H1_N; ic0 += 64) {
      {  // stage chunk (1 item/thread)
        int r = tid >> 6, i = tid & 63;
        float xv = h_lds[r][ic0 + i];
        s_silu[r][i] = silu_f(xv);
        float b[8];
        bspline8(xv, b);
        float4* dst = (float4*)&s_bases[r][i * 8];
        dst[0] = make_float4(b[0], b[1], b[2], b[3]);
        dst[1] = make_float4(b[4], b[5], b[6], b[7]);
      }
      __syncthreads();
      int ib = jh * 16;
      for (int i = ib; i < ib + 16; ++i) {
        int gi = ic0 + i;
        float wb = bwt2[gi * NCLS_N + o2];
        const float4* wp = (const float4*)&swt2[(gi * NCLS_N + o2) * 8];
        float4 w0 = wp[0], w1 = wp[1];
        float sv = s_silu[rr][i];
        const float4* bp = (const float4*)&s_bases[rr][i * 8];
        float4 b0 = bp[0], b1 = bp[1];
        float sp = b0.x * w0.x + b0.y * w0.y + b0.z * w0.z + b0.w * w0.w
                 + b1.x * w1.x + b1.y * w1.y + b1.z * w1.z + b1.w * w1.w;
        acc2 = fmaf(sv, wb, acc2);
        acc2 += sp;
      }
      __syncthreads();
    }
    // reduce 4 jh-partials via the (dead) mean buffer
    float* sac = &mean_sacc[0][0];  // 520 floats >= 512
    sac[jh * 128 + rr * 16 + o2] = acc2;
    __syncthreads();
    if (tid < 128) {
      float s = sac[tid] + sac[128 + tid] + sac[256 + tid] + sac[384 + tid];
      out[(bid * CLPB + (tid >> 4)) * NCLS_N + (tid & 15)] = s;
    }
  }
}

extern "C" void kernel_launch(void* const* d_in, const int* in_sizes, int n_in,
                              void* d_out, int out_size, void* d_ws, size_t ws_size,
                              hipStream_t stream) {
  const float* x   = (const float*)d_in[0];
  const int*   cls = (const int*)d_in[1];
  const float* bw1 = (const float*)d_in[2];
  const float* sw1 = (const float*)d_in[3];
  const float* sc1 = (const float*)d_in[4];
  const float* bw2 = (const float*)d_in[5];
  const float* sw2 = (const float*)d_in[6];
  const float* sc2 = (const float*)d_in[7];
  float* out = (float*)d_out;

  int*   ccnt = (int*)d_ws;                     // 4096         (16 KB)
  int*   spk  = ccnt + K_CLS;                   // 4096*512     (8 MB)
  float* swt1 = (float*)(spk + K_CLS * CAP);    // 64*256*8     (512 KB)
  float* bwt1 = swt1 + C_IN * H1_N * 8;         // 64*256
  float* swt2 = bwt1 + C_IN * H1_N;             // 256*16*8     (128 KB)
  float* bwt2 = swt2 + H1_N * NCLS_N * 8;       // 256*16

  transpose_w<<<C_IN + H1_N / 2 + K_CLS / 256, 256, 0, stream>>>(
      bw1, sw1, sc1, bw2, sw2, sc2, bwt1, swt1, bwt2, swt2, ccnt);
  scatter_atomic<<<SCAT_BLOCKS, 1024, 0, stream>>>(cls, ccnt, spk);
  mega<<<K_CLS / CLPB, 512, 0, stream>>>(
      x, spk, ccnt, bwt1, swt1, bwt2, swt2, out);
}